// Round 1
// baseline (252.557 us; speedup 1.0000x reference)
//
#include <hip/hip_runtime.h>

// Bilinear backward warp, NCHW f32.
// One thread per (h,w) pixel; loop over C channels reusing the 4 gather
// addresses and weights. H,W arrive as device scalars (int*), read in-kernel.
__global__ __launch_bounds__(256) void backward_warp_kernel(
    const float* __restrict__ img,
    const float* __restrict__ flow,
    const int* __restrict__ Hp,
    const int* __restrict__ Wp,
    float* __restrict__ out,
    int HW, int C)
{
    int pix = blockIdx.x * blockDim.x + threadIdx.x;
    if (pix >= HW) return;

    const int W = *Wp;
    const int H = *Hp;
    const int h = pix / W;
    const int w = pix - h * W;

    const float u = flow[pix];
    const float v = flow[HW + pix];

    const float Wm1 = (float)(W - 1);
    const float Hm1 = (float)(H - 1);

    // Replicate the reference's normalize/denormalize round-trip exactly
    // (it's an identity up to fp rounding, but cheap to match bit-for-bit-ish).
    float x = (float)w + u;
    float y = (float)h + v;
    x = 2.0f * (x / Wm1 - 0.5f);
    y = 2.0f * (y / Hm1 - 0.5f);
    x = (x + 1.0f) * 0.5f * Wm1;
    y = (y + 1.0f) * 0.5f * Hm1;

    const float x0 = floorf(x);
    const float x1 = x0 + 1.0f;
    const float y0 = floorf(y);
    const float y1 = y0 + 1.0f;

    // clip-on-float then cast, like the reference
    const int x0c = (int)fminf(fmaxf(x0, 0.0f), Wm1);
    const int x1c = (int)fminf(fmaxf(x1, 0.0f), Wm1);
    const int y0c = (int)fminf(fmaxf(y0, 0.0f), Hm1);
    const int y1c = (int)fminf(fmaxf(y1, 0.0f), Hm1);

    // weights from UNclipped coords (reference semantics)
    const float wa = (x1 - x) * (y1 - y);
    const float wb = (x1 - x) * (y - y0);
    const float wc = (x - x0) * (y1 - y);
    const float wd = (x - x0) * (y - y0);

    const float* pa = img + (size_t)y0c * (size_t)W + x0c;
    const float* pb = img + (size_t)y1c * (size_t)W + x0c;
    const float* pc = img + (size_t)y0c * (size_t)W + x1c;
    const float* pd = img + (size_t)y1c * (size_t)W + x1c;
    float* po = out + pix;

    #pragma unroll 8
    for (int c = 0; c < C; ++c) {
        const size_t off = (size_t)c * (size_t)HW;
        const float Ia = pa[off];
        const float Ib = pb[off];
        const float Ic = pc[off];
        const float Id = pd[off];
        po[off] = wa * Ia + wb * Ib + wc * Ic + wd * Id;
    }
}

extern "C" void kernel_launch(void* const* d_in, const int* in_sizes, int n_in,
                              void* d_out, int out_size, void* d_ws, size_t ws_size,
                              hipStream_t stream) {
    const float* img  = (const float*)d_in[0];
    const float* flow = (const float*)d_in[1];
    const int*   Hp   = (const int*)d_in[2];
    const int*   Wp   = (const int*)d_in[3];
    float* out = (float*)d_out;

    const int HW = in_sizes[1] / 2;          // flow is (1,2,H,W)
    const int C  = in_sizes[0] / HW;         // img is (1,C,H,W)

    const int block = 256;
    const int grid  = (HW + block - 1) / block;
    backward_warp_kernel<<<grid, block, 0, stream>>>(img, flow, Hp, Wp, out, HW, C);
}